// Round 10
// baseline (452.704 us; speedup 1.0000x reference)
//
#include <hip/hip_runtime.h>
#include <stdint.h>

#define B_   32
#define L_   512
#define DT_  4
#define NT_  20
#define SMP_ 50
#define H_   132
#define HPAD 144      // 9 n-tiles of 16 (K4 W image rows)
#define KSTR 136      // bf16 W-image k-stride (shorts)
#define CSTR 148      // K4 clds float stride
#define KCH  5        // 5 k-chunks of 32 (K padded 132 -> 160)
#define NTIL 9
#define WBF_N (HPAD*KSTR)      // 19584 shorts
#define ITILE 16      // k1 i-rows per block
#define SCSTR 520     // k1 score-row stride (shorts)
#define HIDS  136     // k1 hid row stride (floats)
#define HNSTR 160     // hn bf16 image k-stride (shorts, zero-padded 132..159)
#define WDROW 160     // [Win;Wpred] image rows (152 used)
#define NTIL3 10      // k3 n-tiles
#define NROWS (16384*SMP_)     // noise rows
#define NKS   136              // noise image k-stride (shorts; 132 real + 4 zero)
#define NCHUNK (NROWS*(NKS/8)) // 13,926,400 16B-chunks

typedef float  float4v __attribute__((ext_vector_type(4)));
typedef short  short8  __attribute__((ext_vector_type(8)));
typedef unsigned int uint4v __attribute__((ext_vector_type(4)));

#if __has_builtin(__builtin_amdgcn_alignbit)
#define ROTL(x,r) __builtin_amdgcn_alignbit((x),(x),32u-(r))
#else
#define ROTL(x,r) (((x)<<(r))|((x)>>(32u-(r))))
#endif

// ---------------- threefry2x32, key=(0,42), JAX partitionable 32-bit path ------------
// bits[f] = o0 ^ o1 of threefry2x32((0,42), ctr=(0,f))  [verified R5-R9]
__device__ __forceinline__ uint32_t tfpair(uint32_t fa, uint32_t fb){
  const uint32_t ks1 = 42u;
  const uint32_t ks2 = 0x1BD11BDAu ^ 42u;
  uint32_t a0 = 0u, b0 = 0u, a1 = fa + ks1, b1 = fb + ks1;
#define TFR(r) a0+=a1; b0+=b1; a1=ROTL(a1,(r)); b1=ROTL(b1,(r)); a1^=a0; b1^=b0;
  TFR(13) TFR(15) TFR(26) TFR(6)
  a0+=ks1; a1+=ks2+1u; b0+=ks1; b1+=ks2+1u;
  TFR(17) TFR(29) TFR(16) TFR(24)
  a0+=ks2; a1+=2u;     b0+=ks2; b1+=2u;       // ks0+2
  TFR(13) TFR(15) TFR(26) TFR(6)
  a1+=ks1+3u;          b1+=ks1+3u;            // x0+=ks0 (0)
  TFR(17) TFR(29) TFR(16) TFR(24)
  a0+=ks1; a1+=ks2+4u; b0+=ks1; b1+=ks2+4u;
  TFR(13) TFR(15) TFR(26) TFR(6)
  a0+=ks2; a1+=5u;     b0+=ks2; b1+=5u;       // ks0+5
#undef TFR
  uint32_t Ya = ((a0 ^ a1) >> 9) + 0x3f808000u;   // bf16 bits in [31:16], RHU rounding
  uint32_t Yb = ((b0 ^ b1) >> 9) + 0x3f808000u;
#if __has_builtin(__builtin_amdgcn_perm)
  return __builtin_amdgcn_perm(Ya, Yb, 0x03020706u);  // {Yb.hi16, Ya.hi16}
#else
  return (Yb & 0xffff0000u) | (Ya >> 16);
#endif
}

__device__ __forceinline__ float softplus_f(float x){
  return fmaxf(x,0.f) + log1pf(expf(-fabsf(x)));
}

__device__ __forceinline__ short f2bf(float f){   // fp32 -> bf16 RNE
  uint32_t u = __float_as_uint(f);
  u += 0x7fffu + ((u>>16)&1u);
  return (short)(u>>16);
}

__device__ __forceinline__ float bf_round(float f){   // fp32 -> bf16 -> fp32
  uint32_t u = __float_as_uint(f);
  u += 0x7fffu + ((u>>16)&1u);
  u &= 0xffff0000u;
  return __uint_as_float(u);
}

// ---------------- K0: embeddings (bf16 hv image) + per-event scalars ----------------
__global__ __launch_bounds__(64) void k0_embed(
    const int* __restrict__ etype, const float* __restrict__ etime,
    const float* __restrict__ Wt,  const float* __restrict__ temb,
    const float* __restrict__ Wg,  const float* __restrict__ Wl,
    uint16_t* __restrict__ hv_bf, float* __restrict__ sc4, float* __restrict__ outmean){
  int bl = blockIdx.x;
  int l  = bl & (L_-1);
  int k  = threadIdx.x;                 // 0..63
  float t = etime[bl];
  const float M = -0.07195578414202429f;  // -ln(10000)/128
  float dterm = expf((float)(2*k) * M);
  float ang = (float)l * dterm + t * Wt[k];
  float sv, cv;
  sincosf(ang, &sv, &cv);
  hv_bf[(size_t)bl*H_ + k]      = (uint16_t)f2bf(sv);
  hv_bf[(size_t)bl*H_ + 64 + k] = (uint16_t)f2bf(cv);
  int et = etype[bl];
  if (k < 4) hv_bf[(size_t)bl*H_ + 128 + k] = (uint16_t)f2bf(temb[et*4 + k]);
  if (k == 0){
    float t0 = temb[et*4+0], t1 = temb[et*4+1], t2 = temb[et*4+2], t3 = temb[et*4+3];
    sc4[bl*4+0] = t0*Wg[0]+t1*Wg[1]+t2*Wg[2]+t3*Wg[3];  // dg  (j-side)
    sc4[bl*4+1] = t0*Wg[4]+t1*Wg[5]+t2*Wg[6]+t3*Wg[7];  // dg2 (i-side)
    sc4[bl*4+2] = t0*Wl[0]+t1*Wl[1]+t2*Wl[2]+t3*Wl[3];  // dl
    sc4[bl*4+3] = t0*Wl[4]+t1*Wl[5]+t2*Wl[6]+t3*Wl[7];  // dl2
    outmean[bl] = 0.f;   // zero accumulator for K4 atomics (out is poisoned 0xAA)
  }
}

// ---------------- K_noise: materialize bf16 noise image (split path) ----------------
// chunk c (16B = 8 elems): row = c/17, k0 = (c%17)*8; f = row*132 + k0.
// k >= 132 slots written as 0 (zero pad; GEMM A-tail relies on it).
__global__ __launch_bounds__(256) void k_noise(uint32_t* __restrict__ noise){
  uint32_t c = blockIdx.x*256 + threadIdx.x;
  if (c >= NCHUNK) return;
  uint32_t row = c / 17u;
  uint32_t k0  = (c - row*17u)*8u;
  uint32_t f   = row*132u + k0;
  uint4v st;
  #pragma unroll
  for (int t = 0; t < 4; ++t){
    uint32_t v = tfpair(f + 2*t, f + 2*t + 1);
    st[t] = (k0 + 2*t < 132u) ? v : 0u;
  }
  ((uint4v*)noise)[c] = st;
}

// ---------------- K_prep: bf16 W images. blocks 0..8: W_noise (+rowsum);
// blocks 9..18: [W_in; W_pred] rows 0..159 (152 real, rest zero) ----------------
__global__ __launch_bounds__(256) void k_prep(const float* __restrict__ Wn,
                                              const float* __restrict__ Win,
                                              const float* __restrict__ Wpred,
                                              uint16_t* __restrict__ wbf,
                                              uint16_t* __restrict__ wd,
                                              float* __restrict__ rs){
  int blk = blockIdx.x, tid = threadIdx.x;
  if (blk < 9){
    for (int e = tid; e < 16*KSTR; e += 256){
      int r = e / KSTR, k = e - r*KSTR;
      int n = blk*16 + r;
      uint16_t v = 0;
      if (n < H_ && k < H_) v = (uint16_t)f2bf(Wn[n*H_ + k]);
      wbf[n*KSTR + k] = v;
    }
    if (tid < 16){
      int n = blk*16 + tid;
      if (n < H_){
        float s = 0.f;
        const float* row = Wn + (size_t)n*H_;
        #pragma unroll 4
        for (int k = 0; k < H_; ++k) s += bf_round(row[k]);
        rs[n] = s;
      }
    }
  } else {
    int rb = blk - 9;                  // 0..9
    for (int e = tid; e < 16*KSTR; e += 256){
      int r = e / KSTR, k = e - r*KSTR;
      int n = rb*16 + r;
      uint16_t v = 0;
      if (k < H_){
        if (n < H_)            v = (uint16_t)f2bf(Win[n*H_ + k]);
        else if (n < H_+NT_)   v = (uint16_t)f2bf(Wpred[(n-H_)*H_ + k]);
      }
      wd[n*KSTR + k] = v;
    }
  }
}

// ---------------- K1: gated-kernel attention as MFMA flash-tile + fused LN ----------
__global__ __launch_bounds__(256) void k1_attn(
    const float* __restrict__ etime, const float* __restrict__ sc4,
    const uint16_t* __restrict__ hv_bf,
    const float* __restrict__ bgp, const float* __restrict__ blp,
    const float* __restrict__ gamma, const float* __restrict__ beta,
    uint16_t* __restrict__ hn_bf){
  __shared__ __align__(16) uint16_t scb[ITILE*SCSTR];
  __shared__ float jt[L_], jg[L_], jl[L_];
  __shared__ float rt[ITILE], rg[ITILE], rl[ITILE];
  __shared__ __align__(16) float hid[ITILE*HIDS];
  __shared__ float mur[ITILE], rsr[ITILE];
  int i0 = blockIdx.x*ITILE, b = blockIdx.y, base = b*L_;
  int tid = threadIdx.x;
  float bg = bgp[0], blv = blp[0];
  for (int j = tid; j < L_; j += 256){
    jt[j] = etime[base+j];
    jg[j] = sc4[(base+j)*4+0];
    jl[j] = sc4[(base+j)*4+2];
  }
  if (tid < ITILE){
    rt[tid] = etime[base+i0+tid];
    rg[tid] = sc4[(base+i0+tid)*4+1];
    rl[tid] = sc4[(base+i0+tid)*4+3];
  }
  __syncthreads();
  // phase 1: score tile (causal zeros exact in bf16)
  for (int e = tid; e < ITILE*L_; e += 256){
    int r = e >> 9, j = e & (L_-1);
    float v = 0.f;
    if (j < i0 + r){
      float gate = 1.f/(1.f+expf(-(jg[j] + rg[r] + bg)));
      float ls   = softplus_f(jl[j] + rl[r] + blv) + 1e-6f;
      float d    = rt[r] - jt[j];
      v = gate / (1.f + d*d/(2.f*ls*ls));
    }
    scb[r*SCSTR + j] = (uint16_t)f2bf(v);
  }
  __syncthreads();
  // phase 2: hidden[16][H] = scores @ hv  (MFMA 16x16x32)
  int wave = tid>>6, lane = tid&63, q = lane>>4, col = lane&15;
  const uint16_t* hvb = hv_bf + (size_t)base*H_;
  for (int nt = wave; nt < NTIL; nt += 4){
    float4v acc = {0.f,0.f,0.f,0.f};
    int n = nt*16 + col;
    for (int kt = 0; kt < 16; ++kt){
      short8 af = *(const short8*)&scb[col*SCSTR + kt*32 + q*8];  // A[m=col][k]
      short8 bfr = {0,0,0,0,0,0,0,0};
      if (n < H_){
        int kb = kt*32 + q*8;
        #pragma unroll
        for (int j = 0; j < 8; ++j)
          bfr[j] = (short)hvb[(size_t)(kb+j)*H_ + n];             // B[k][n]
      }
      acc = __builtin_amdgcn_mfma_f32_16x16x32_bf16(af, bfr, acc, 0, 0, 0);
    }
    if (n < H_){
      #pragma unroll
      for (int rr = 0; rr < 4; ++rr)
        hid[(q*4+rr)*HIDS + n] = acc[rr];    // C/D: row=q*4+rr, col=n
    }
  }
  __syncthreads();
  // LayerNorm stats: wave w handles rows 4w..4w+3
  #pragma unroll
  for (int rr = 0; rr < 4; ++rr){
    int r = wave*4 + rr;
    float x0 = hid[r*HIDS + lane];
    float x1 = hid[r*HIDS + 64 + lane];
    float x2 = (lane<4) ? hid[r*HIDS + 128 + lane] : 0.f;
    float s1 = x0+x1+x2, s2 = x0*x0+x1*x1+x2*x2;
    #pragma unroll
    for (int m=32; m; m>>=1){ s1 += __shfl_xor(s1, m, 64); s2 += __shfl_xor(s2, m, 64); }
    if (lane == 0){
      float mu = s1 * (1.f/132.f);
      float var = s2 * (1.f/132.f) - mu*mu;
      mur[r] = mu; rsr[r] = rsqrtf(var + 1e-6f);
    }
  }
  __syncthreads();
  if (tid < HNSTR){
    if (tid < H_){
      float g = gamma[tid], be = beta[tid];
      #pragma unroll 4
      for (int r = 0; r < ITILE; ++r)
        hn_bf[(size_t)(base+i0+r)*HNSTR + tid] =
            (uint16_t)f2bf((hid[r*HIDS+tid]-mur[r])*rsr[r]*g + be);
    } else {
      #pragma unroll 4
      for (int r = 0; r < ITILE; ++r)
        hn_bf[(size_t)(base+i0+r)*HNSTR + tid] = 0;   // zero pad k=132..159
    }
  }
}

// ---------------- K3: MFMA decoder ----------------
__global__ __launch_bounds__(256) void k3_dec(
    const uint16_t* __restrict__ hn_bf, const uint16_t* __restrict__ wd,
    float* __restrict__ cvec, float* __restrict__ outp){
  __shared__ float logit[64*NT_];
  int tid = threadIdx.x, wave = tid>>6, lane = tid&63, q = lane>>4, col = lane&15;
  int row0 = blockIdx.x*64;
  int r0 = row0 + wave*16;
  short8 afr[KCH];
  #pragma unroll
  for (int kc = 0; kc < KCH; ++kc)
    afr[kc] = *(const short8*)&hn_bf[(size_t)(r0+col)*HNSTR + kc*32 + q*8]; // A[m=col][k]
  for (int nt = 0; nt < NTIL3; ++nt){
    float4v acc = {0.f,0.f,0.f,0.f};
    const short8* bp = (const short8*)&wd[(nt*16+col)*KSTR];
    #pragma unroll
    for (int kc = 0; kc < KCH; ++kc){
      // kc=4,q>0 reads past row end: A is zero at k>=132 (hn pad) -- harmless
      short8 bfr = bp[kc*4 + q];     // B[n=col][k]
      acc = __builtin_amdgcn_mfma_f32_16x16x32_bf16(afr[kc], bfr, acc, 0, 0, 0);
    }
    int n = nt*16 + col;             // C/D: row=q*4+rr, col=n
    #pragma unroll
    for (int rr = 0; rr < 4; ++rr){
      int lr = wave*16 + q*4 + rr;   // local row 0..63
      if (n < H_)            cvec[(size_t)(row0+lr)*H_ + n] = acc[rr];
      else if (n < H_+NT_)   logit[lr*NT_ + (n-H_)] = acc[rr];
    }
  }
  __syncthreads();
  if (tid < 64){
    float mx = -1e30f;
    #pragma unroll
    for (int j=0;j<NT_;++j) mx = fmaxf(mx, logit[tid*NT_+j]);
    float ex[NT_]; float ssum = 0.f;
    #pragma unroll
    for (int j=0;j<NT_;++j){ ex[j] = expf(logit[tid*NT_+j]-mx); ssum += ex[j]; }
    float inv = 1.f/ssum;
    #pragma unroll
    for (int j=0;j<NT_;++j)
      outp[(size_t)(B_*L_) + (size_t)(row0+tid)*NT_ + j] = ex[j]*inv;
  }
}

// ---------------- shared K4 body: staging + GEMM epilogue ----------------
// A-fragments come either from tfpair (fused) or the noise image (split).
#define K4_STAGE_AND_PROLOG \
  __shared__ __align__(16) short Wlds[WBF_N]; \
  __shared__ __align__(16) float clds[16*CSTR]; \
  __shared__ float wtlds[HPAD]; \
  __shared__ float part[128]; \
  int tid = threadIdx.x, lane = tid & 63; \
  int l0 = blockIdx.x*16, b = blockIdx.y, sch = blockIdx.z; \
  int bl0 = b*L_ + l0; \
  { const uint4v* g = (const uint4v*)wbf; uint4v* l = (uint4v*)Wlds; \
    for (int idx = tid; idx < WBF_N/8; idx += 512) l[idx] = g[idx]; } \
  for (int m = tid>>6; m < 16; m += 8){ \
    for (int n = lane; n < CSTR; n += 64){ \
      float v = 0.f; \
      if (n < H_) v = cvec[(size_t)(bl0+m)*H_ + n] - rs[n]; \
      clds[m*CSTR + n] = v; } } \
  if (tid < HPAD) wtlds[tid] = (tid < H_) ? wt[tid] : 0.f; \
  if (tid < 128) part[tid] = 0.f; \
  __syncthreads(); \
  int wave = tid >> 6; \
  int q = lane >> 4, col = lane & 15; \
  int s = sch*8 + wave;

#define K4_GEMM_AND_EPILOG \
    float racc0=0.f, racc1=0.f, racc2=0.f, racc3=0.f; \
    for (int nt = 0; nt < NTIL; ++nt){ \
      float4v acc = {0.f,0.f,0.f,0.f}; \
      const short8* bp = (const short8*)&Wlds[(nt*16+col)*KSTR]; \
      _Pragma("unroll") \
      for (int kc = 0; kc < KCH; ++kc){ \
        short8 bfr = bp[kc*4 + q]; \
        acc = __builtin_amdgcn_mfma_f32_16x16x32_bf16( \
                 __builtin_bit_cast(short8, afu[kc]), bfr, acc, 0, 0, 0); \
      } \
      int n = nt*16 + col; \
      float wv = wtlds[n]; \
      const float* cb = &clds[(q*4)*CSTR + n]; \
      racc0 += fmaxf(acc[0] + cb[0*CSTR], 0.f)*wv; \
      racc1 += fmaxf(acc[1] + cb[1*CSTR], 0.f)*wv; \
      racc2 += fmaxf(acc[2] + cb[2*CSTR], 0.f)*wv; \
      racc3 += fmaxf(acc[3] + cb[3*CSTR], 0.f)*wv; \
    } \
    _Pragma("unroll") \
    for (int m = 1; m < 16; m <<= 1){ \
      racc0 += __shfl_xor(racc0, m, 64); \
      racc1 += __shfl_xor(racc1, m, 64); \
      racc2 += __shfl_xor(racc2, m, 64); \
      racc3 += __shfl_xor(racc3, m, 64); \
    } \
    if (col == 0){ \
      part[wave*16 + q*4 + 0] = 0.02f * softplus_f(racc0); \
      part[wave*16 + q*4 + 1] = 0.02f * softplus_f(racc1); \
      part[wave*16 + q*4 + 2] = 0.02f * softplus_f(racc2); \
      part[wave*16 + q*4 + 3] = 0.02f * softplus_f(racc3); \
    }

#define K4_REDUCE \
  __syncthreads(); \
  if (tid < 16){ \
    float v = 0.f; \
    _Pragma("unroll") \
    for (int w = 0; w < 8; ++w) v += part[w*16 + tid]; \
    atomicAdd(&outmean[bl0 + tid], v); \
  }

// ---------------- K4 fused (fallback, R9-identical semantics) ----------------
__global__ __launch_bounds__(512, 6) void k4_sampler(
    const uint16_t* __restrict__ wbf, const float* __restrict__ cvec,
    const float* __restrict__ wt, const float* __restrict__ rs,
    float* __restrict__ outmean){
  K4_STAGE_AND_PROLOG
  if (s < SMP_){
    uint32_t fbase = (uint32_t)(bl0 + col)*(uint32_t)(SMP_*H_)
                   + (uint32_t)s*(uint32_t)H_ + (uint32_t)(q*8);
    uint4v afu[KCH];
    #pragma unroll
    for (int kc = 0; kc < 4; ++kc){
      #pragma unroll
      for (int t = 0; t < 4; ++t)
        afu[kc][t] = tfpair(fbase + (uint32_t)(kc*32 + 2*t),
                            fbase + (uint32_t)(kc*32 + 2*t + 1));
    }
    {
      uint4v a4 = {0u,0u,0u,0u};
      if (q == 0){
        a4[0] = tfpair(fbase + 128u, fbase + 129u);
        a4[1] = tfpair(fbase + 130u, fbase + 131u);
      }
      afu[4] = a4;
    }
    K4_GEMM_AND_EPILOG
  }
  K4_REDUCE
}

// ---------------- K4 split-GEMM: A-frags loaded from noise image ----------------
__global__ __launch_bounds__(512, 6) void k4_gemm(
    const uint16_t* __restrict__ wbf, const float* __restrict__ cvec,
    const float* __restrict__ wt, const float* __restrict__ rs,
    const uint32_t* __restrict__ noise, float* __restrict__ outmean){
  K4_STAGE_AND_PROLOG
  if (s < SMP_){
    // noise row (bl0+col, s): NKS/8 = 17 uint4 chunks; chunk = kc*4+q
    const uint4v* nrow = (const uint4v*)noise
                       + ((size_t)(bl0 + col)*SMP_ + (size_t)s)*(NKS/8);
    uint4v afu[KCH];
    #pragma unroll
    for (int kc = 0; kc < 4; ++kc) afu[kc] = nrow[kc*4 + q];
    {
      uint4v a4 = {0u,0u,0u,0u};
      if (q == 0) a4 = nrow[16];     // k=128..135 (132..135 are zero-padded)
      afu[4] = a4;
    }
    K4_GEMM_AND_EPILOG
  }
  K4_REDUCE
}

// ---------------- launch ----------------
extern "C" void kernel_launch(void* const* d_in, const int* in_sizes, int n_in,
                              void* d_out, int out_size, void* d_ws, size_t ws_size,
                              hipStream_t stream){
  const int*   etype = (const int*)  d_in[0];
  const float* etime = (const float*)d_in[1];
  const float* Wt    = (const float*)d_in[3];
  const float* temb  = (const float*)d_in[4];
  const float* Wg    = (const float*)d_in[5];
  const float* bgp   = (const float*)d_in[6];
  const float* Wl    = (const float*)d_in[7];
  const float* blp   = (const float*)d_in[8];
  const float* gamma = (const float*)d_in[9];
  const float* beta  = (const float*)d_in[10];
  const float* Win   = (const float*)d_in[11];
  const float* Wn    = (const float*)d_in[12];
  const float* wtm   = (const float*)d_in[13];
  const float* Wpred = (const float*)d_in[14];
  float* out = (float*)d_out;

  uint16_t* hv_bf  = (uint16_t*)d_ws;                       // 16384*132 shorts
  float*    sc4    = (float*)(hv_bf + (size_t)16384*H_);    // 16384*4 floats
  float*    cvec   = sc4    + (size_t)16384*4;              // 16384*132 floats
  float*    rs     = cvec   + (size_t)16384*H_;             // 132 (+pad to 256)
  uint16_t* hn_bf  = (uint16_t*)(rs + 256);                 // 16384*160 shorts
  uint16_t* wbf    = hn_bf  + (size_t)16384*HNSTR;          // HPAD*KSTR shorts
  uint16_t* wd     = wbf    + (size_t)WBF_N;                // WDROW*KSTR shorts
  uint32_t* noise  = (uint32_t*)(wd + (size_t)WDROW*KSTR);  // 16B-chunk noise image
  size_t need = ((char*)noise - (char*)d_ws) + (size_t)NROWS*NKS*2;
  bool split = (ws_size >= need);

  k0_embed  <<<dim3(16384),     dim3(64),  0, stream>>>(etype, etime, Wt, temb, Wg, Wl, hv_bf, sc4, out);
  k_prep    <<<dim3(19),        dim3(256), 0, stream>>>(Wn, Win, Wpred, wbf, wd, rs);
  if (split)
    k_noise <<<dim3((NCHUNK+255)/256), dim3(256), 0, stream>>>(noise);
  k1_attn   <<<dim3(32,32),     dim3(256), 0, stream>>>(etime, sc4, hv_bf, bgp, blp, gamma, beta, hn_bf);
  k3_dec    <<<dim3(256),       dim3(256), 0, stream>>>(hn_bf, wd, cvec, out);
  if (split)
    k4_gemm <<<dim3(32,32,7),   dim3(512), 0, stream>>>(wbf, cvec, wtm, rs, noise, out);
  else
    k4_sampler<<<dim3(32,32,7), dim3(512), 0, stream>>>(wbf, cvec, wtm, rs, out);
}

// Round 11
// 401.005 us; speedup vs baseline: 1.1289x; 1.1289x over previous
//
#include <hip/hip_runtime.h>
#include <stdint.h>

#define B_   32
#define L_   512
#define DT_  4
#define NT_  20
#define SMP_ 50
#define H_   132
#define HPAD 144      // padded feature rows (9 n-tiles of 16)
#define KSTR 136      // bf16 W-image k-stride (shorts)
#define CSTR 148      // K4 clds float stride
#define KCH  5        // 5 k-chunks of 32 (K padded 132 -> 160)
#define NTIL 9
#define WBF_N (HPAD*KSTR)      // 19584 shorts
#define ITILE 16      // k1 i-rows per block
#define SCSTR 520     // k1 score-row stride (shorts)
#define HIDS  136     // k1 hid row stride (floats)
#define HNLS  160     // k1 fused-decoder hn LDS row stride (shorts)
#define WDROW 160     // [Win;Wpred] image rows (152 used)
#define NTIL3 10      // decoder n-tiles

typedef float  float4v __attribute__((ext_vector_type(4)));
typedef short  short8  __attribute__((ext_vector_type(8)));
typedef unsigned int uint4v __attribute__((ext_vector_type(4)));

#if __has_builtin(__builtin_amdgcn_alignbit)
#define ROTL(x,r) __builtin_amdgcn_alignbit((x),(x),32u-(r))
#else
#define ROTL(x,r) (((x)<<(r))|((x)>>(32u-(r))))
#endif

// ---------------- threefry2x32, key=(0,42), JAX partitionable 32-bit path ------------
// bits[f] = o0 ^ o1 of threefry2x32((0,42), ctr=(0,f))  [verified R5-R10]
__device__ __forceinline__ uint32_t tfpair(uint32_t fa, uint32_t fb){
  const uint32_t ks1 = 42u;
  const uint32_t ks2 = 0x1BD11BDAu ^ 42u;
  uint32_t a0 = 0u, b0 = 0u, a1 = fa + ks1, b1 = fb + ks1;
#define TFR(r) a0+=a1; b0+=b1; a1=ROTL(a1,(r)); b1=ROTL(b1,(r)); a1^=a0; b1^=b0;
  TFR(13) TFR(15) TFR(26) TFR(6)
  a0+=ks1; a1+=ks2+1u; b0+=ks1; b1+=ks2+1u;
  TFR(17) TFR(29) TFR(16) TFR(24)
  a0+=ks2; a1+=2u;     b0+=ks2; b1+=2u;       // ks0+2
  TFR(13) TFR(15) TFR(26) TFR(6)
  a1+=ks1+3u;          b1+=ks1+3u;            // x0+=ks0 (0)
  TFR(17) TFR(29) TFR(16) TFR(24)
  a0+=ks1; a1+=ks2+4u; b0+=ks1; b1+=ks2+4u;
  TFR(13) TFR(15) TFR(26) TFR(6)
  a0+=ks2; a1+=5u;     b0+=ks2; b1+=5u;       // ks0+5
#undef TFR
  uint32_t Ya = ((a0 ^ a1) >> 9) + 0x3f808000u;   // bf16 bits in [31:16], RHU rounding
  uint32_t Yb = ((b0 ^ b1) >> 9) + 0x3f808000u;
#if __has_builtin(__builtin_amdgcn_perm)
  return __builtin_amdgcn_perm(Ya, Yb, 0x03020706u);  // {Yb.hi16, Ya.hi16}
#else
  return (Yb & 0xffff0000u) | (Ya >> 16);
#endif
}

__device__ __forceinline__ float softplus_fast(float x){
  return fmaxf(x,0.f) + __logf(1.f + __expf(-fabsf(x)));
}

__device__ __forceinline__ float softplus_f(float x){
  return fmaxf(x,0.f) + log1pf(expf(-fabsf(x)));
}

__device__ __forceinline__ short f2bf(float f){   // fp32 -> bf16 RNE
  uint32_t u = __float_as_uint(f);
  u += 0x7fffu + ((u>>16)&1u);
  return (short)(u>>16);
}

__device__ __forceinline__ float bf_round(float f){   // fp32 -> bf16 -> fp32
  uint32_t u = __float_as_uint(f);
  u += 0x7fffu + ((u>>16)&1u);
  u &= 0xffff0000u;
  return __uint_as_float(u);
}

// ---------------- K0: embeddings (transposed bf16 hvT image) + scalars + prep -------
// blocks 0..4095: 4 (b,l) positions each (256 thr). blocks 4096..4117: prep work.
__global__ __launch_bounds__(256) void k0_embed(
    const int* __restrict__ etype, const float* __restrict__ etime,
    const float* __restrict__ Wt,  const float* __restrict__ temb,
    const float* __restrict__ Wg,  const float* __restrict__ Wl,
    const float* __restrict__ Wn,  const float* __restrict__ Win,
    const float* __restrict__ Wpred,
    uint16_t* __restrict__ hvT, float* __restrict__ sc4, float* __restrict__ outmean,
    uint16_t* __restrict__ wbf, uint16_t* __restrict__ wd, float* __restrict__ rs){
  int blk = blockIdx.x, tid = threadIdx.x;
  if (blk < 4096){
    int bl = blk*4 + (tid>>6);
    int b  = bl >> 9, l = bl & (L_-1);
    int k  = tid & 63;
    float t = etime[bl];
    const float M = -0.07195578414202429f;  // -ln(10000)/128
    float dterm = __expf((float)(2*k) * M);
    float ang = (float)l * dterm + t * Wt[k];
    float sv, cv;
    sincosf(ang, &sv, &cv);
    uint16_t* hb = hvT + (size_t)b*HPAD*L_;
    hb[(size_t)k*L_ + l]      = (uint16_t)f2bf(sv);
    hb[(size_t)(64+k)*L_ + l] = (uint16_t)f2bf(cv);
    int et = etype[bl];
    if (k < 4) hb[(size_t)(128+k)*L_ + l] = (uint16_t)f2bf(temb[et*4 + k]);
    if (k == 0){
      float t0 = temb[et*4+0], t1 = temb[et*4+1], t2 = temb[et*4+2], t3 = temb[et*4+3];
      sc4[bl*4+0] = t0*Wg[0]+t1*Wg[1]+t2*Wg[2]+t3*Wg[3];  // dg  (j-side)
      sc4[bl*4+1] = t0*Wg[4]+t1*Wg[5]+t2*Wg[6]+t3*Wg[7];  // dg2 (i-side)
      sc4[bl*4+2] = t0*Wl[0]+t1*Wl[1]+t2*Wl[2]+t3*Wl[3];  // dl
      sc4[bl*4+3] = t0*Wl[4]+t1*Wl[5]+t2*Wl[6]+t3*Wl[7];  // dl2
      outmean[bl] = 0.f;   // zero accumulator for K4 atomics
    }
  } else {
    int pb = blk - 4096;               // 0..21
    if (pb < 9){                       // W_noise bf16 image + rowsum(bf16 W)
      for (int e = tid; e < 16*KSTR; e += 256){
        int r = e / KSTR, k = e - r*KSTR;
        int n = pb*16 + r;
        uint16_t v = 0;
        if (n < H_ && k < H_) v = (uint16_t)f2bf(Wn[n*H_ + k]);
        wbf[n*KSTR + k] = v;
      }
      if (tid < 16){
        int n = pb*16 + tid;
        if (n < H_){
          float s = 0.f;
          const float* row = Wn + (size_t)n*H_;
          #pragma unroll 4
          for (int k = 0; k < H_; ++k) s += bf_round(row[k]);
          rs[n] = s;
        }
      }
    } else if (pb < 19){               // [Win; Wpred] bf16 image
      int rb = pb - 9;                 // 0..9
      for (int e = tid; e < 16*KSTR; e += 256){
        int r = e / KSTR, k = e - r*KSTR;
        int n = rb*16 + r;
        uint16_t v = 0;
        if (k < H_){
          if (n < H_)          v = (uint16_t)f2bf(Win[n*H_ + k]);
          else if (n < H_+NT_) v = (uint16_t)f2bf(Wpred[(n-H_)*H_ + k]);
        }
        wd[n*KSTR + k] = v;
      }
    } else {                           // zero hvT pad rows 132..143 (all batches)
      int e0 = (pb - 19)*65536;        // 3 blocks x 65536 = 196608 = 32*12*512
      for (int i = tid; i < 65536; i += 256){
        int e = e0 + i;
        int b = e / (12*L_);
        int rem = e - b*(12*L_);
        int n = 132 + (rem >> 9);
        int l = rem & (L_-1);
        hvT[((size_t)b*HPAD + n)*L_ + l] = 0;
      }
    }
  }
}

// ---------------- K1: attention flash-tile + LN + fused decoder (ex-k3) -------------
// grid (32,32) x 256 thr. Phase1: 16x512 score tile (bf16 LDS). Phase2: scores @ hv
// via MFMA, B-frags = short8 from hvT. LN. Then decoder: hn(16x132) @ [Win;Wpred]^T
// -> cvec + softmax(mark_probs).
__global__ __launch_bounds__(256) void k1_attn(
    const float* __restrict__ etime, const float* __restrict__ sc4,
    const uint16_t* __restrict__ hvT, const uint16_t* __restrict__ wd,
    const float* __restrict__ bgp, const float* __restrict__ blp,
    const float* __restrict__ gamma, const float* __restrict__ beta,
    float* __restrict__ cvec, float* __restrict__ outp){
  __shared__ __align__(16) uint16_t scb[ITILE*SCSTR];
  __shared__ float jt[L_], jg[L_], jl[L_];
  __shared__ float rt[ITILE], rg[ITILE], rl[ITILE];
  __shared__ __align__(16) float hid[ITILE*HIDS];
  __shared__ __align__(16) uint16_t hnl[ITILE*HNLS];
  __shared__ float logit[ITILE*NT_];
  __shared__ float mur[ITILE], rsr[ITILE];
  int i0 = blockIdx.x*ITILE, b = blockIdx.y, base = b*L_;
  int tid = threadIdx.x;
  float bg = bgp[0], blv = blp[0];
  for (int j = tid; j < L_; j += 256){
    jt[j] = etime[base+j];
    jg[j] = sc4[(base+j)*4+0];
    jl[j] = sc4[(base+j)*4+2];
  }
  if (tid < ITILE){
    rt[tid] = etime[base+i0+tid];
    rg[tid] = sc4[(base+i0+tid)*4+1];
    rl[tid] = sc4[(base+i0+tid)*4+3];
  }
  __syncthreads();
  // phase 1: score tile (fast transcendentals; causal zeros exact in bf16)
  for (int e = tid; e < ITILE*L_; e += 256){
    int r = e >> 9, j = e & (L_-1);
    float v = 0.f;
    if (j < i0 + r){
      float gate = __frcp_rn(1.f + __expf(-(jg[j] + rg[r] + bg)));
      float ls   = softplus_fast(jl[j] + rl[r] + blv) + 1e-6f;
      float d    = rt[r] - jt[j];
      float t2   = 2.f*ls*ls;
      v = gate * t2 * __frcp_rn(t2 + d*d);
    }
    scb[r*SCSTR + j] = (uint16_t)f2bf(v);
  }
  __syncthreads();
  // phase 2: hidden[16][H] = scores @ hv  (MFMA 16x16x32, B from hvT short8)
  int wave = tid>>6, lane = tid&63, q = lane>>4, col = lane&15;
  for (int nt = wave; nt < NTIL; nt += 4){
    float4v acc = {0.f,0.f,0.f,0.f};
    int n = nt*16 + col;
    const uint16_t* bT = hvT + ((size_t)b*HPAD + n)*L_;   // row valid (144 rows, pad=0)
    for (int kt = 0; kt < 16; ++kt){
      short8 af  = *(const short8*)&scb[col*SCSTR + kt*32 + q*8];  // A[m=col][k]
      short8 bfr = *(const short8*)&bT[kt*32 + q*8];               // B[k][n] contiguous k
      acc = __builtin_amdgcn_mfma_f32_16x16x32_bf16(af, bfr, acc, 0, 0, 0);
    }
    if (n < H_){
      #pragma unroll
      for (int rr = 0; rr < 4; ++rr)
        hid[(q*4+rr)*HIDS + n] = acc[rr];    // C/D: row=q*4+rr, col=n
    }
  }
  __syncthreads();
  // LayerNorm stats: wave w handles rows 4w..4w+3
  #pragma unroll
  for (int rr = 0; rr < 4; ++rr){
    int r = wave*4 + rr;
    float x0 = hid[r*HIDS + lane];
    float x1 = hid[r*HIDS + 64 + lane];
    float x2 = (lane<4) ? hid[r*HIDS + 128 + lane] : 0.f;
    float s1 = x0+x1+x2, s2 = x0*x0+x1*x1+x2*x2;
    #pragma unroll
    for (int m=32; m; m>>=1){ s1 += __shfl_xor(s1, m, 64); s2 += __shfl_xor(s2, m, 64); }
    if (lane == 0){
      float mu = s1 * (1.f/132.f);
      float var = s2 * (1.f/132.f) - mu*mu;
      mur[r] = mu; rsr[r] = rsqrtf(var + 1e-6f);
    }
  }
  __syncthreads();
  // hn rows -> bf16 LDS (zero-padded k=132..159)
  if (tid < HNLS){
    if (tid < H_){
      float g = gamma[tid], be = beta[tid];
      #pragma unroll 4
      for (int r = 0; r < ITILE; ++r)
        hnl[r*HNLS + tid] = (uint16_t)f2bf((hid[r*HIDS+tid]-mur[r])*rsr[r]*g + be);
    } else {
      #pragma unroll 4
      for (int r = 0; r < ITILE; ++r) hnl[r*HNLS + tid] = 0;
    }
  }
  __syncthreads();
  // fused decoder: hn(16x132) @ wd(152x132)^T -> cvec (n<132) + logits (132..151)
  short8 afr[KCH];
  #pragma unroll
  for (int kc = 0; kc < KCH; ++kc)
    afr[kc] = *(const short8*)&hnl[col*HNLS + kc*32 + q*8];   // A[m=col][k]
  for (int nt = wave; nt < NTIL3; nt += 4){
    float4v acc = {0.f,0.f,0.f,0.f};
    const short8* bp = (const short8*)&wd[(nt*16+col)*KSTR];
    #pragma unroll
    for (int kc = 0; kc < KCH; ++kc){
      // kc=4,q>0 reads past wd row end: A is zero at k>=132 -- harmless (finite garbage)
      short8 bfr = bp[kc*4 + q];     // B[n=col within tile][k]
      acc = __builtin_amdgcn_mfma_f32_16x16x32_bf16(afr[kc], bfr, acc, 0, 0, 0);
    }
    int n = nt*16 + col;             // C/D: row=q*4+rr, col=n
    #pragma unroll
    for (int rr = 0; rr < 4; ++rr){
      int lr = q*4 + rr;             // local row 0..15
      if (n < H_)            cvec[(size_t)(base+i0+lr)*H_ + n] = acc[rr];
      else if (n < H_+NT_)   logit[lr*NT_ + (n-H_)] = acc[rr];
    }
  }
  __syncthreads();
  if (tid < ITILE){
    float mx = -1e30f;
    #pragma unroll
    for (int j=0;j<NT_;++j) mx = fmaxf(mx, logit[tid*NT_+j]);
    float ex[NT_]; float ssum = 0.f;
    #pragma unroll
    for (int j=0;j<NT_;++j){ ex[j] = __expf(logit[tid*NT_+j]-mx); ssum += ex[j]; }
    float inv = __frcp_rn(ssum);
    #pragma unroll
    for (int j=0;j<NT_;++j)
      outp[(size_t)(B_*L_) + (size_t)(base+i0+tid)*NT_ + j] = ex[j]*inv;
  }
}

// ---------------- K4: GAN sampler (fused, R9-identical) ----------------
__global__ __launch_bounds__(512, 6) void k4_sampler(
    const uint16_t* __restrict__ wbf, const float* __restrict__ cvec,
    const float* __restrict__ wt, const float* __restrict__ rs,
    float* __restrict__ outmean){
  __shared__ __align__(16) short Wlds[WBF_N];
  __shared__ __align__(16) float clds[16*CSTR];
  __shared__ float wtlds[HPAD];
  __shared__ float part[128];
  int tid = threadIdx.x, lane = tid & 63;
  int l0 = blockIdx.x*16, b = blockIdx.y, sch = blockIdx.z;
  int bl0 = b*L_ + l0;

  {   // stage W: flat 2448 x 16B vector copy
    const uint4v* g = (const uint4v*)wbf;
    uint4v* l = (uint4v*)Wlds;
    for (int idx = tid; idx < WBF_N/8; idx += 512) l[idx] = g[idx];
  }
  for (int m = tid>>6; m < 16; m += 8){
    for (int n = lane; n < CSTR; n += 64){
      float v = 0.f;
      if (n < H_) v = cvec[(size_t)(bl0+m)*H_ + n] - rs[n];
      clds[m*CSTR + n] = v;
    }
  }
  if (tid < HPAD) wtlds[tid] = (tid < H_) ? wt[tid] : 0.f;
  if (tid < 128) part[tid] = 0.f;
  __syncthreads();

  int wave = tid >> 6;
  int q = lane >> 4, col = lane & 15;
  int s = sch*8 + wave;
  if (s < SMP_){
    uint32_t fbase = (uint32_t)(bl0 + col)*(uint32_t)(SMP_*H_)
                   + (uint32_t)s*(uint32_t)H_ + (uint32_t)(q*8);
    uint4v afu[KCH];
    #pragma unroll
    for (int kc = 0; kc < 4; ++kc){
      #pragma unroll
      for (int t = 0; t < 4; ++t)
        afu[kc][t] = tfpair(fbase + (uint32_t)(kc*32 + 2*t),
                            fbase + (uint32_t)(kc*32 + 2*t + 1));
    }
    {
      uint4v a4 = {0u,0u,0u,0u};
      if (q == 0){
        a4[0] = tfpair(fbase + 128u, fbase + 129u);
        a4[1] = tfpair(fbase + 130u, fbase + 131u);
      }
      afu[4] = a4;
    }
    float racc0=0.f, racc1=0.f, racc2=0.f, racc3=0.f;
    for (int nt = 0; nt < NTIL; ++nt){
      float4v acc = {0.f,0.f,0.f,0.f};
      const short8* bp = (const short8*)&Wlds[(nt*16+col)*KSTR];
      #pragma unroll
      for (int kc = 0; kc < KCH; ++kc){
        short8 bfr = bp[kc*4 + q];
        acc = __builtin_amdgcn_mfma_f32_16x16x32_bf16(
                 __builtin_bit_cast(short8, afu[kc]), bfr, acc, 0, 0, 0);
      }
      int n = nt*16 + col;
      float wv = wtlds[n];
      const float* cb = &clds[(q*4)*CSTR + n];
      racc0 += fmaxf(acc[0] + cb[0*CSTR], 0.f)*wv;
      racc1 += fmaxf(acc[1] + cb[1*CSTR], 0.f)*wv;
      racc2 += fmaxf(acc[2] + cb[2*CSTR], 0.f)*wv;
      racc3 += fmaxf(acc[3] + cb[3*CSTR], 0.f)*wv;
    }
    #pragma unroll
    for (int m = 1; m < 16; m <<= 1){
      racc0 += __shfl_xor(racc0, m, 64);
      racc1 += __shfl_xor(racc1, m, 64);
      racc2 += __shfl_xor(racc2, m, 64);
      racc3 += __shfl_xor(racc3, m, 64);
    }
    if (col == 0){
      part[wave*16 + q*4 + 0] = 0.02f * softplus_f(racc0);
      part[wave*16 + q*4 + 1] = 0.02f * softplus_f(racc1);
      part[wave*16 + q*4 + 2] = 0.02f * softplus_f(racc2);
      part[wave*16 + q*4 + 3] = 0.02f * softplus_f(racc3);
    }
  }
  __syncthreads();
  if (tid < 16){
    float v = 0.f;
    #pragma unroll
    for (int w = 0; w < 8; ++w) v += part[w*16 + tid];
    atomicAdd(&outmean[bl0 + tid], v);
  }
}

// ---------------- launch ----------------
extern "C" void kernel_launch(void* const* d_in, const int* in_sizes, int n_in,
                              void* d_out, int out_size, void* d_ws, size_t ws_size,
                              hipStream_t stream){
  const int*   etype = (const int*)  d_in[0];
  const float* etime = (const float*)d_in[1];
  const float* Wt    = (const float*)d_in[3];
  const float* temb  = (const float*)d_in[4];
  const float* Wg    = (const float*)d_in[5];
  const float* bgp   = (const float*)d_in[6];
  const float* Wl    = (const float*)d_in[7];
  const float* blp   = (const float*)d_in[8];
  const float* gamma = (const float*)d_in[9];
  const float* beta  = (const float*)d_in[10];
  const float* Win   = (const float*)d_in[11];
  const float* Wn    = (const float*)d_in[12];
  const float* wtm   = (const float*)d_in[13];
  const float* Wpred = (const float*)d_in[14];
  float* out = (float*)d_out;

  uint16_t* hvT   = (uint16_t*)d_ws;                        // 32*144*512 shorts
  float*    sc4   = (float*)(hvT + (size_t)B_*HPAD*L_);     // 16384*4 floats
  float*    cvec  = sc4 + (size_t)16384*4;                  // 16384*132 floats
  float*    rs    = cvec + (size_t)16384*H_;                // 132 (+pad to 256)
  uint16_t* wbf   = (uint16_t*)(rs + 256);                  // HPAD*KSTR shorts
  uint16_t* wd    = wbf + (size_t)WBF_N;                    // WDROW*KSTR shorts

  k0_embed  <<<dim3(4118),      dim3(256), 0, stream>>>(etype, etime, Wt, temb, Wg, Wl,
                                                        Wn, Win, Wpred, hvT, sc4, out, wbf, wd, rs);
  k1_attn   <<<dim3(32,32),     dim3(256), 0, stream>>>(etime, sc4, hvT, wd, bgp, blp,
                                                        gamma, beta, cvec, out);
  k4_sampler<<<dim3(32,32,7),   dim3(512), 0, stream>>>(wbf, cvec, wtm, rs, out);
}

// Round 12
// 390.744 us; speedup vs baseline: 1.1586x; 1.0263x over previous
//
#include <hip/hip_runtime.h>
#include <stdint.h>

#define B_   32
#define L_   512
#define DT_  4
#define NT_  20
#define SMP_ 50
#define H_   132
#define HPAD 144      // padded feature rows (9 n-tiles of 16)
#define KSTR 136      // bf16 W-image k-stride (shorts)
#define CSTR 148      // K4 clds float stride
#define KCH  5        // 5 k-chunks of 32 (K padded 132 -> 160)
#define NTIL 9
#define WBF_N (HPAD*KSTR)      // 19584 shorts
#define ITILE 16      // k1 i-rows per block
#define SCSTR 520     // k1 score-row stride (shorts)
#define HIDS  136     // k1 hid row stride (floats)
#define HNLS  160     // k1 fused-decoder hn LDS row stride (shorts)
#define WDROW 160     // [Win;Wpred] image rows (152 used)
#define NTIL3 10      // decoder n-tiles

typedef float  float4v __attribute__((ext_vector_type(4)));
typedef short  short8  __attribute__((ext_vector_type(8)));
typedef unsigned int uint4v __attribute__((ext_vector_type(4)));

// R12: prefer the standard clang rotate builtin (guaranteed fshl -> v_alignbit);
// prior guard chain may have silently fallen through to a 3-op rotate.
#if __has_builtin(__builtin_rotateleft32)
#define ROTL(x,r) __builtin_rotateleft32((x),(r))
#elif __has_builtin(__builtin_amdgcn_alignbit)
#define ROTL(x,r) __builtin_amdgcn_alignbit((x),(x),32u-(r))
#else
#define ROTL(x,r) (((x)<<(r))|((x)>>(32u-(r))))
#endif

// ---------------- threefry2x32, key=(0,42), JAX partitionable 32-bit path ------------
// bits[f] = o0 ^ o1 of threefry2x32((0,42), ctr=(0,f))  [verified R5-R11]
__device__ __forceinline__ uint32_t tfpair(uint32_t fa, uint32_t fb){
  const uint32_t ks1 = 42u;
  const uint32_t ks2 = 0x1BD11BDAu ^ 42u;
  uint32_t a0 = 0u, b0 = 0u, a1 = fa + ks1, b1 = fb + ks1;
#define TFR(r) a0+=a1; b0+=b1; a1=ROTL(a1,(r)); b1=ROTL(b1,(r)); a1^=a0; b1^=b0;
  TFR(13) TFR(15) TFR(26) TFR(6)
  a0+=ks1; a1+=ks2+1u; b0+=ks1; b1+=ks2+1u;
  TFR(17) TFR(29) TFR(16) TFR(24)
  a0+=ks2; a1+=2u;     b0+=ks2; b1+=2u;       // ks0+2
  TFR(13) TFR(15) TFR(26) TFR(6)
  a1+=ks1+3u;          b1+=ks1+3u;            // x0+=ks0 (0)
  TFR(17) TFR(29) TFR(16) TFR(24)
  a0+=ks1; a1+=ks2+4u; b0+=ks1; b1+=ks2+4u;
  TFR(13) TFR(15) TFR(26) TFR(6)
  a0+=ks2; a1+=5u;     b0+=ks2; b1+=5u;       // ks0+5
#undef TFR
  uint32_t Ya = ((a0 ^ a1) >> 9) + 0x3f808000u;   // bf16 bits in [31:16], RHU rounding
  uint32_t Yb = ((b0 ^ b1) >> 9) + 0x3f808000u;
#if __has_builtin(__builtin_amdgcn_perm)
  return __builtin_amdgcn_perm(Ya, Yb, 0x03020706u);  // {Yb.hi16, Ya.hi16}
#else
  return (Yb & 0xffff0000u) | (Ya >> 16);
#endif
}

__device__ __forceinline__ float softplus_fast(float x){
  return fmaxf(x,0.f) + __logf(1.f + __expf(-fabsf(x)));
}

__device__ __forceinline__ float softplus_f(float x){
  return fmaxf(x,0.f) + log1pf(expf(-fabsf(x)));
}

__device__ __forceinline__ short f2bf(float f){   // fp32 -> bf16 RNE
  uint32_t u = __float_as_uint(f);
  u += 0x7fffu + ((u>>16)&1u);
  return (short)(u>>16);
}

__device__ __forceinline__ float bf_round(float f){   // fp32 -> bf16 -> fp32
  uint32_t u = __float_as_uint(f);
  u += 0x7fffu + ((u>>16)&1u);
  u &= 0xffff0000u;
  return __uint_as_float(u);
}

// ---------------- K0: embeddings -> transposed bf16 hvT image (coalesced) -----------
// blocks 0..127: (b, l-tile of 128). LDS-staged 144x128 tile, 256B-row writes.
// blocks 128..146: W-image prep (wbf+rs, wd).
__global__ __launch_bounds__(256) void k0_embed(
    const int* __restrict__ etype, const float* __restrict__ etime,
    const float* __restrict__ Wt,  const float* __restrict__ temb,
    const float* __restrict__ Wg,  const float* __restrict__ Wl,
    const float* __restrict__ Wn,  const float* __restrict__ Win,
    const float* __restrict__ Wpred,
    uint16_t* __restrict__ hvT, float* __restrict__ sc4, float* __restrict__ outmean,
    uint16_t* __restrict__ wbf, uint16_t* __restrict__ wd, float* __restrict__ rs){
  int blk = blockIdx.x, tid = threadIdx.x;
  if (blk < 128){
    __shared__ __align__(16) uint16_t tile[HPAD*128];   // 36864 B
    __shared__ float tvec[128];
    int b = blk >> 2, l0 = (blk & 3)*128;
    int base = b*L_ + l0;
    if (tid < 128) tvec[tid] = etime[base + tid];
    __syncthreads();
    const float M = -0.07195578414202429f;  // -ln(10000)/128
    // sin/cos rows 0..127: 8192 entries; lane-consecutive p -> conflict-free LDS
    for (int rep = 0; rep < 32; ++rep){
      int idx = rep*256 + tid;
      int k = idx >> 7, p = idx & 127;
      float dterm = __expf((float)(2*k) * M);
      float ang = (float)(l0 + p) * dterm + tvec[p] * Wt[k];
      float sv, cv;
      sincosf(ang, &sv, &cv);
      tile[k*128 + p]      = (uint16_t)f2bf(sv);
      tile[(64+k)*128 + p] = (uint16_t)f2bf(cv);
    }
    // rows 128..143: type emb (128..131) + zero pad (132..143)
    for (int rep = 0; rep < 8; ++rep){
      int idx = rep*256 + tid;
      int r = 128 + (idx >> 7), p = idx & 127;
      uint16_t v = 0;
      if (r < 132){
        int et = etype[base + p];
        v = (uint16_t)f2bf(temb[et*4 + (r-128)]);
      }
      tile[r*128 + p] = v;
    }
    // per-position scalars
    if (tid < 128){
      int bl = base + tid;
      int et = etype[bl];
      float t0 = temb[et*4+0], t1 = temb[et*4+1], t2 = temb[et*4+2], t3 = temb[et*4+3];
      sc4[bl*4+0] = t0*Wg[0]+t1*Wg[1]+t2*Wg[2]+t3*Wg[3];  // dg  (j-side)
      sc4[bl*4+1] = t0*Wg[4]+t1*Wg[5]+t2*Wg[6]+t3*Wg[7];  // dg2 (i-side)
      sc4[bl*4+2] = t0*Wl[0]+t1*Wl[1]+t2*Wl[2]+t3*Wl[3];  // dl
      sc4[bl*4+3] = t0*Wl[4]+t1*Wl[5]+t2*Wl[6]+t3*Wl[7];  // dl2
      outmean[bl] = 0.f;   // zero accumulator for K4 atomics
    }
    __syncthreads();
    // coalesced write-out: 144 rows x 16 uint4 (256B per row)
    for (int pass = 0; pass < 9; ++pass){
      int r = pass*16 + (tid>>4);
      int c = tid & 15;
      ((uint4v*)(hvT + ((size_t)b*HPAD + r)*L_ + l0))[c] = ((const uint4v*)(tile + r*128))[c];
    }
  } else {
    int pb = blk - 128;                // 0..18
    if (pb < 9){                       // W_noise bf16 image + rowsum(bf16 W)
      for (int e = tid; e < 16*KSTR; e += 256){
        int r = e / KSTR, k = e - r*KSTR;
        int n = pb*16 + r;
        uint16_t v = 0;
        if (n < H_ && k < H_) v = (uint16_t)f2bf(Wn[n*H_ + k]);
        wbf[n*KSTR + k] = v;
      }
      if (tid < 16){
        int n = pb*16 + tid;
        if (n < H_){
          float s = 0.f;
          const float* row = Wn + (size_t)n*H_;
          #pragma unroll 4
          for (int k = 0; k < H_; ++k) s += bf_round(row[k]);
          rs[n] = s;
        }
      }
    } else {                           // [Win; Wpred] bf16 image
      int rb = pb - 9;                 // 0..9
      for (int e = tid; e < 16*KSTR; e += 256){
        int r = e / KSTR, k = e - r*KSTR;
        int n = rb*16 + r;
        uint16_t v = 0;
        if (k < H_){
          if (n < H_)          v = (uint16_t)f2bf(Win[n*H_ + k]);
          else if (n < H_+NT_) v = (uint16_t)f2bf(Wpred[(n-H_)*H_ + k]);
        }
        wd[n*KSTR + k] = v;
      }
    }
  }
}

// ---------------- K1: attention flash-tile + LN + fused decoder ----------------
__global__ __launch_bounds__(256) void k1_attn(
    const float* __restrict__ etime, const float* __restrict__ sc4,
    const uint16_t* __restrict__ hvT, const uint16_t* __restrict__ wd,
    const float* __restrict__ bgp, const float* __restrict__ blp,
    const float* __restrict__ gamma, const float* __restrict__ beta,
    float* __restrict__ cvec, float* __restrict__ outp){
  __shared__ __align__(16) uint16_t scb[ITILE*SCSTR];
  __shared__ float jt[L_], jg[L_], jl[L_];
  __shared__ float rt[ITILE], rg[ITILE], rl[ITILE];
  __shared__ __align__(16) float hid[ITILE*HIDS];
  __shared__ __align__(16) uint16_t hnl[ITILE*HNLS];
  __shared__ float logit[ITILE*NT_];
  __shared__ float mur[ITILE], rsr[ITILE];
  int i0 = blockIdx.x*ITILE, b = blockIdx.y, base = b*L_;
  int tid = threadIdx.x;
  float bg = bgp[0], blv = blp[0];
  for (int j = tid; j < L_; j += 256){
    jt[j] = etime[base+j];
    jg[j] = sc4[(base+j)*4+0];
    jl[j] = sc4[(base+j)*4+2];
  }
  if (tid < ITILE){
    rt[tid] = etime[base+i0+tid];
    rg[tid] = sc4[(base+i0+tid)*4+1];
    rl[tid] = sc4[(base+i0+tid)*4+3];
  }
  __syncthreads();
  // phase 1: score tile (fast transcendentals; causal zeros exact in bf16)
  for (int e = tid; e < ITILE*L_; e += 256){
    int r = e >> 9, j = e & (L_-1);
    float v = 0.f;
    if (j < i0 + r){
      float gate = __frcp_rn(1.f + __expf(-(jg[j] + rg[r] + bg)));
      float ls   = softplus_fast(jl[j] + rl[r] + blv) + 1e-6f;
      float d    = rt[r] - jt[j];
      float t2   = 2.f*ls*ls;
      v = gate * t2 * __frcp_rn(t2 + d*d);
    }
    scb[r*SCSTR + j] = (uint16_t)f2bf(v);
  }
  __syncthreads();
  // phase 2: hidden[16][H] = scores @ hv  (MFMA 16x16x32, B from hvT short8)
  int wave = tid>>6, lane = tid&63, q = lane>>4, col = lane&15;
  for (int nt = wave; nt < NTIL; nt += 4){
    float4v acc = {0.f,0.f,0.f,0.f};
    int n = nt*16 + col;
    const uint16_t* bT = hvT + ((size_t)b*HPAD + n)*L_;   // 144 rows, pad rows zero
    for (int kt = 0; kt < 16; ++kt){
      short8 af  = *(const short8*)&scb[col*SCSTR + kt*32 + q*8];  // A[m=col][k]
      short8 bfr = *(const short8*)&bT[kt*32 + q*8];               // B[k][n]
      acc = __builtin_amdgcn_mfma_f32_16x16x32_bf16(af, bfr, acc, 0, 0, 0);
    }
    if (n < H_){
      #pragma unroll
      for (int rr = 0; rr < 4; ++rr)
        hid[(q*4+rr)*HIDS + n] = acc[rr];    // C/D: row=q*4+rr, col=n
    }
  }
  __syncthreads();
  // LayerNorm stats
  #pragma unroll
  for (int rr = 0; rr < 4; ++rr){
    int r = wave*4 + rr;
    float x0 = hid[r*HIDS + lane];
    float x1 = hid[r*HIDS + 64 + lane];
    float x2 = (lane<4) ? hid[r*HIDS + 128 + lane] : 0.f;
    float s1 = x0+x1+x2, s2 = x0*x0+x1*x1+x2*x2;
    #pragma unroll
    for (int m=32; m; m>>=1){ s1 += __shfl_xor(s1, m, 64); s2 += __shfl_xor(s2, m, 64); }
    if (lane == 0){
      float mu = s1 * (1.f/132.f);
      float var = s2 * (1.f/132.f) - mu*mu;
      mur[r] = mu; rsr[r] = rsqrtf(var + 1e-6f);
    }
  }
  __syncthreads();
  if (tid < HNLS){
    if (tid < H_){
      float g = gamma[tid], be = beta[tid];
      #pragma unroll 4
      for (int r = 0; r < ITILE; ++r)
        hnl[r*HNLS + tid] = (uint16_t)f2bf((hid[r*HIDS+tid]-mur[r])*rsr[r]*g + be);
    } else {
      #pragma unroll 4
      for (int r = 0; r < ITILE; ++r) hnl[r*HNLS + tid] = 0;
    }
  }
  __syncthreads();
  // fused decoder: hn(16x132) @ wd(152x132)^T -> cvec + logits
  short8 afr[KCH];
  #pragma unroll
  for (int kc = 0; kc < KCH; ++kc)
    afr[kc] = *(const short8*)&hnl[col*HNLS + kc*32 + q*8];   // A[m=col][k]
  for (int nt = wave; nt < NTIL3; nt += 4){
    float4v acc = {0.f,0.f,0.f,0.f};
    const short8* bp = (const short8*)&wd[(nt*16+col)*KSTR];
    #pragma unroll
    for (int kc = 0; kc < KCH; ++kc){
      // kc=4,q>0 reads past wd row end: A zero at k>=132 -- harmless
      short8 bfr = bp[kc*4 + q];
      acc = __builtin_amdgcn_mfma_f32_16x16x32_bf16(afr[kc], bfr, acc, 0, 0, 0);
    }
    int n = nt*16 + col;
    #pragma unroll
    for (int rr = 0; rr < 4; ++rr){
      int lr = q*4 + rr;
      if (n < H_)            cvec[(size_t)(base+i0+lr)*H_ + n] = acc[rr];
      else if (n < H_+NT_)   logit[lr*NT_ + (n-H_)] = acc[rr];
    }
  }
  __syncthreads();
  if (tid < ITILE){
    float mx = -1e30f;
    #pragma unroll
    for (int j=0;j<NT_;++j) mx = fmaxf(mx, logit[tid*NT_+j]);
    float ex[NT_]; float ssum = 0.f;
    #pragma unroll
    for (int j=0;j<NT_;++j){ ex[j] = __expf(logit[tid*NT_+j]-mx); ssum += ex[j]; }
    float inv = __frcp_rn(ssum);
    #pragma unroll
    for (int j=0;j<NT_;++j)
      outp[(size_t)(B_*L_) + (size_t)(base+i0+tid)*NT_ + j] = ex[j]*inv;
  }
}

// ---------------- K4: GAN sampler (fused, R9-identical structure) ----------------
__global__ __launch_bounds__(512, 6) void k4_sampler(
    const uint16_t* __restrict__ wbf, const float* __restrict__ cvec,
    const float* __restrict__ wt, const float* __restrict__ rs,
    float* __restrict__ outmean){
  __shared__ __align__(16) short Wlds[WBF_N];
  __shared__ __align__(16) float clds[16*CSTR];
  __shared__ float wtlds[HPAD];
  __shared__ float part[128];
  int tid = threadIdx.x, lane = tid & 63;
  int l0 = blockIdx.x*16, b = blockIdx.y, sch = blockIdx.z;
  int bl0 = b*L_ + l0;

  {   // stage W: flat 2448 x 16B vector copy
    const uint4v* g = (const uint4v*)wbf;
    uint4v* l = (uint4v*)Wlds;
    for (int idx = tid; idx < WBF_N/8; idx += 512) l[idx] = g[idx];
  }
  for (int m = tid>>6; m < 16; m += 8){
    for (int n = lane; n < CSTR; n += 64){
      float v = 0.f;
      if (n < H_) v = cvec[(size_t)(bl0+m)*H_ + n] - rs[n];
      clds[m*CSTR + n] = v;
    }
  }
  if (tid < HPAD) wtlds[tid] = (tid < H_) ? wt[tid] : 0.f;
  if (tid < 128) part[tid] = 0.f;
  __syncthreads();

  int wave = tid >> 6;
  int q = lane >> 4, col = lane & 15;
  int s = sch*8 + wave;
  if (s < SMP_){
    uint32_t fbase = (uint32_t)(bl0 + col)*(uint32_t)(SMP_*H_)
                   + (uint32_t)s*(uint32_t)H_ + (uint32_t)(q*8);
    uint4v afu[KCH];
    #pragma unroll
    for (int kc = 0; kc < 4; ++kc){
      #pragma unroll
      for (int t = 0; t < 4; ++t)
        afu[kc][t] = tfpair(fbase + (uint32_t)(kc*32 + 2*t),
                            fbase + (uint32_t)(kc*32 + 2*t + 1));
    }
    {
      uint4v a4 = {0u,0u,0u,0u};
      if (q == 0){
        a4[0] = tfpair(fbase + 128u, fbase + 129u);
        a4[1] = tfpair(fbase + 130u, fbase + 131u);
      }
      afu[4] = a4;
    }
    float racc0=0.f, racc1=0.f, racc2=0.f, racc3=0.f;
    for (int nt = 0; nt < NTIL; ++nt){
      float4v acc = {0.f,0.f,0.f,0.f};
      const short8* bp = (const short8*)&Wlds[(nt*16+col)*KSTR];
      #pragma unroll
      for (int kc = 0; kc < KCH; ++kc){
        short8 bfr = bp[kc*4 + q];
        acc = __builtin_amdgcn_mfma_f32_16x16x32_bf16(
                 __builtin_bit_cast(short8, afu[kc]), bfr, acc, 0, 0, 0);
      }
      int n = nt*16 + col;
      float wv = wtlds[n];
      const float* cb = &clds[(q*4)*CSTR + n];
      racc0 += fmaxf(acc[0] + cb[0*CSTR], 0.f)*wv;
      racc1 += fmaxf(acc[1] + cb[1*CSTR], 0.f)*wv;
      racc2 += fmaxf(acc[2] + cb[2*CSTR], 0.f)*wv;
      racc3 += fmaxf(acc[3] + cb[3*CSTR], 0.f)*wv;
    }
    #pragma unroll
    for (int m = 1; m < 16; m <<= 1){
      racc0 += __shfl_xor(racc0, m, 64);
      racc1 += __shfl_xor(racc1, m, 64);
      racc2 += __shfl_xor(racc2, m, 64);
      racc3 += __shfl_xor(racc3, m, 64);
    }
    if (col == 0){
      part[wave*16 + q*4 + 0] = 0.02f * softplus_f(racc0);
      part[wave*16 + q*4 + 1] = 0.02f * softplus_f(racc1);
      part[wave*16 + q*4 + 2] = 0.02f * softplus_f(racc2);
      part[wave*16 + q*4 + 3] = 0.02f * softplus_f(racc3);
    }
  }
  __syncthreads();
  if (tid < 16){
    float v = 0.f;
    #pragma unroll
    for (int w = 0; w < 8; ++w) v += part[w*16 + tid];
    atomicAdd(&outmean[bl0 + tid], v);
  }
}

// ---------------- launch ----------------
extern "C" void kernel_launch(void* const* d_in, const int* in_sizes, int n_in,
                              void* d_out, int out_size, void* d_ws, size_t ws_size,
                              hipStream_t stream){
  const int*   etype = (const int*)  d_in[0];
  const float* etime = (const float*)d_in[1];
  const float* Wt    = (const float*)d_in[3];
  const float* temb  = (const float*)d_in[4];
  const float* Wg    = (const float*)d_in[5];
  const float* bgp   = (const float*)d_in[6];
  const float* Wl    = (const float*)d_in[7];
  const float* blp   = (const float*)d_in[8];
  const float* gamma = (const float*)d_in[9];
  const float* beta  = (const float*)d_in[10];
  const float* Win   = (const float*)d_in[11];
  const float* Wn    = (const float*)d_in[12];
  const float* wtm   = (const float*)d_in[13];
  const float* Wpred = (const float*)d_in[14];
  float* out = (float*)d_out;

  uint16_t* hvT   = (uint16_t*)d_ws;                        // 32*144*512 shorts
  float*    sc4   = (float*)(hvT + (size_t)B_*HPAD*L_);     // 16384*4 floats
  float*    cvec  = sc4 + (size_t)16384*4;                  // 16384*132 floats
  float*    rs    = cvec + (size_t)16384*H_;                // 132 (+pad to 256)
  uint16_t* wbf   = (uint16_t*)(rs + 256);                  // HPAD*KSTR shorts
  uint16_t* wd    = wbf + (size_t)WBF_N;                    // WDROW*KSTR shorts

  k0_embed  <<<dim3(147),       dim3(256), 0, stream>>>(etype, etime, Wt, temb, Wg, Wl,
                                                        Wn, Win, Wpred, hvT, sc4, out, wbf, wd, rs);
  k1_attn   <<<dim3(32,32),     dim3(256), 0, stream>>>(etime, sc4, hvT, wd, bgp, blp,
                                                        gamma, beta, cvec, out);
  k4_sampler<<<dim3(32,32,7),   dim3(512), 0, stream>>>(wbf, cvec, wtm, rs, out);
}

// Round 13
// 390.249 us; speedup vs baseline: 1.1600x; 1.0013x over previous
//
#include <hip/hip_runtime.h>
#include <stdint.h>

#define B_   32
#define L_   512
#define DT_  4
#define NT_  20
#define SMP_ 50
#define H_   132
#define HPAD 144      // padded feature rows (9 n-tiles of 16)
#define KSTR 136      // bf16 W-image k-stride (shorts)
#define CSTR 148      // K4 clds float stride
#define KCH  5        // 5 k-chunks of 32 (K padded 132 -> 160)
#define NTIL 9
#define WBF_N (HPAD*KSTR)      // 19584 shorts
#define ITILE 16      // k1 i-rows per block
#define SCSTR 520     // k1 score-row stride (shorts)
#define HIDS  136     // k1 hid row stride (floats)
#define HNLS  160     // k1 fused-decoder hn LDS row stride (shorts)
#define WDROW 160     // [Win;Wpred] image rows (152 used)
#define NTIL3 10      // decoder n-tiles

typedef float  float4v __attribute__((ext_vector_type(4)));
typedef short  short8  __attribute__((ext_vector_type(8)));
typedef unsigned int uint4v __attribute__((ext_vector_type(4)));

#if __has_builtin(__builtin_rotateleft32)
#define ROTL(x,r) __builtin_rotateleft32((x),(r))
#elif __has_builtin(__builtin_amdgcn_alignbit)
#define ROTL(x,r) __builtin_amdgcn_alignbit((x),(x),32u-(r))
#else
#define ROTL(x,r) (((x)<<(r))|((x)>>(32u-(r))))
#endif

// ---------------- threefry2x32, key=(0,42), JAX partitionable 32-bit path ------------
// bits[f] = o0 ^ o1 of threefry2x32((0,42), ctr=(0,f))  [verified R5-R12]
__device__ __forceinline__ uint32_t tfpair(uint32_t fa, uint32_t fb){
  const uint32_t ks1 = 42u;
  const uint32_t ks2 = 0x1BD11BDAu ^ 42u;
  uint32_t a0 = 0u, b0 = 0u, a1 = fa + ks1, b1 = fb + ks1;
#define TFR(r) a0+=a1; b0+=b1; a1=ROTL(a1,(r)); b1=ROTL(b1,(r)); a1^=a0; b1^=b0;
  TFR(13) TFR(15) TFR(26) TFR(6)
  a0+=ks1; a1+=ks2+1u; b0+=ks1; b1+=ks2+1u;
  TFR(17) TFR(29) TFR(16) TFR(24)
  a0+=ks2; a1+=2u;     b0+=ks2; b1+=2u;       // ks0+2
  TFR(13) TFR(15) TFR(26) TFR(6)
  a1+=ks1+3u;          b1+=ks1+3u;            // x0+=ks0 (0)
  TFR(17) TFR(29) TFR(16) TFR(24)
  a0+=ks1; a1+=ks2+4u; b0+=ks1; b1+=ks2+4u;
  TFR(13) TFR(15) TFR(26) TFR(6)
  a0+=ks2; a1+=5u;     b0+=ks2; b1+=5u;       // ks0+5
#undef TFR
  uint32_t Ya = ((a0 ^ a1) >> 9) + 0x3f808000u;   // bf16 bits in [31:16], RHU rounding
  uint32_t Yb = ((b0 ^ b1) >> 9) + 0x3f808000u;
#if __has_builtin(__builtin_amdgcn_perm)
  return __builtin_amdgcn_perm(Ya, Yb, 0x03020706u);  // {Yb.hi16, Ya.hi16}
#else
  return (Yb & 0xffff0000u) | (Ya >> 16);
#endif
}

__device__ __forceinline__ float softplus_fast(float x){
  return fmaxf(x,0.f) + __logf(1.f + __expf(-fabsf(x)));
}

__device__ __forceinline__ float softplus_f(float x){
  return fmaxf(x,0.f) + log1pf(expf(-fabsf(x)));
}

__device__ __forceinline__ short f2bf(float f){   // fp32 -> bf16 RNE
  uint32_t u = __float_as_uint(f);
  u += 0x7fffu + ((u>>16)&1u);
  return (short)(u>>16);
}

__device__ __forceinline__ float bf_round(float f){   // fp32 -> bf16 -> fp32
  uint32_t u = __float_as_uint(f);
  u += 0x7fffu + ((u>>16)&1u);
  u &= 0xffff0000u;
  return __uint_as_float(u);
}

// ---------------- K0: embeddings -> transposed bf16 hvT image (coalesced) -----------
__global__ __launch_bounds__(256) void k0_embed(
    const int* __restrict__ etype, const float* __restrict__ etime,
    const float* __restrict__ Wt,  const float* __restrict__ temb,
    const float* __restrict__ Wg,  const float* __restrict__ Wl,
    const float* __restrict__ Wn,  const float* __restrict__ Win,
    const float* __restrict__ Wpred,
    uint16_t* __restrict__ hvT, float* __restrict__ sc4, float* __restrict__ outmean,
    uint16_t* __restrict__ wbf, uint16_t* __restrict__ wd, float* __restrict__ rs){
  int blk = blockIdx.x, tid = threadIdx.x;
  if (blk < 128){
    __shared__ __align__(16) uint16_t tile[HPAD*128];   // 36864 B
    __shared__ float tvec[128];
    int b = blk >> 2, l0 = (blk & 3)*128;
    int base = b*L_ + l0;
    if (tid < 128) tvec[tid] = etime[base + tid];
    __syncthreads();
    const float M = -0.07195578414202429f;  // -ln(10000)/128
    for (int rep = 0; rep < 32; ++rep){
      int idx = rep*256 + tid;
      int k = idx >> 7, p = idx & 127;
      float dterm = __expf((float)(2*k) * M);
      float ang = (float)(l0 + p) * dterm + tvec[p] * Wt[k];
      float sv, cv;
      sincosf(ang, &sv, &cv);
      tile[k*128 + p]      = (uint16_t)f2bf(sv);
      tile[(64+k)*128 + p] = (uint16_t)f2bf(cv);
    }
    for (int rep = 0; rep < 8; ++rep){
      int idx = rep*256 + tid;
      int r = 128 + (idx >> 7), p = idx & 127;
      uint16_t v = 0;
      if (r < 132){
        int et = etype[base + p];
        v = (uint16_t)f2bf(temb[et*4 + (r-128)]);
      }
      tile[r*128 + p] = v;
    }
    if (tid < 128){
      int bl = base + tid;
      int et = etype[bl];
      float t0 = temb[et*4+0], t1 = temb[et*4+1], t2 = temb[et*4+2], t3 = temb[et*4+3];
      sc4[bl*4+0] = t0*Wg[0]+t1*Wg[1]+t2*Wg[2]+t3*Wg[3];  // dg  (j-side)
      sc4[bl*4+1] = t0*Wg[4]+t1*Wg[5]+t2*Wg[6]+t3*Wg[7];  // dg2 (i-side)
      sc4[bl*4+2] = t0*Wl[0]+t1*Wl[1]+t2*Wl[2]+t3*Wl[3];  // dl
      sc4[bl*4+3] = t0*Wl[4]+t1*Wl[5]+t2*Wl[6]+t3*Wl[7];  // dl2
      outmean[bl] = 0.f;
    }
    __syncthreads();
    for (int pass = 0; pass < 9; ++pass){
      int r = pass*16 + (tid>>4);
      int c = tid & 15;
      ((uint4v*)(hvT + ((size_t)b*HPAD + r)*L_ + l0))[c] = ((const uint4v*)(tile + r*128))[c];
    }
  } else {
    int pb = blk - 128;                // 0..18
    if (pb < 9){                       // W_noise bf16 image + rowsum(bf16 W)
      for (int e = tid; e < 16*KSTR; e += 256){
        int r = e / KSTR, k = e - r*KSTR;
        int n = pb*16 + r;
        uint16_t v = 0;
        if (n < H_ && k < H_) v = (uint16_t)f2bf(Wn[n*H_ + k]);
        wbf[n*KSTR + k] = v;
      }
      if (tid < 16){
        int n = pb*16 + tid;
        if (n < H_){
          float s = 0.f;
          const float* row = Wn + (size_t)n*H_;
          #pragma unroll 4
          for (int k = 0; k < H_; ++k) s += bf_round(row[k]);
          rs[n] = s;
        }
      }
    } else {                           // [Win; Wpred] bf16 image
      int rb = pb - 9;                 // 0..9
      for (int e = tid; e < 16*KSTR; e += 256){
        int r = e / KSTR, k = e - r*KSTR;
        int n = rb*16 + r;
        uint16_t v = 0;
        if (k < H_){
          if (n < H_)          v = (uint16_t)f2bf(Win[n*H_ + k]);
          else if (n < H_+NT_) v = (uint16_t)f2bf(Wpred[(n-H_)*H_ + k]);
        }
        wd[n*KSTR + k] = v;
      }
    }
  }
}

// ---------------- K1: attention flash-tile + LN + fused decoder ----------------
// R13: phase-2 kt loop fully unrolled -> 16 independent B-loads in flight per nt
// (was a rolled load->MFMA dependent chain, ~200cy L2 latency per iteration).
__global__ __launch_bounds__(256) void k1_attn(
    const float* __restrict__ etime, const float* __restrict__ sc4,
    const uint16_t* __restrict__ hvT, const uint16_t* __restrict__ wd,
    const float* __restrict__ bgp, const float* __restrict__ blp,
    const float* __restrict__ gamma, const float* __restrict__ beta,
    float* __restrict__ cvec, float* __restrict__ outp){
  __shared__ __align__(16) uint16_t scb[ITILE*SCSTR];
  __shared__ float jt[L_], jg[L_], jl[L_];
  __shared__ float rt[ITILE], rg[ITILE], rl[ITILE];
  __shared__ __align__(16) float hid[ITILE*HIDS];
  __shared__ __align__(16) uint16_t hnl[ITILE*HNLS];
  __shared__ float logit[ITILE*NT_];
  __shared__ float mur[ITILE], rsr[ITILE];
  int i0 = blockIdx.x*ITILE, b = blockIdx.y, base = b*L_;
  int tid = threadIdx.x;
  float bg = bgp[0], blv = blp[0];
  for (int j = tid; j < L_; j += 256){
    jt[j] = etime[base+j];
    jg[j] = sc4[(base+j)*4+0];
    jl[j] = sc4[(base+j)*4+2];
  }
  if (tid < ITILE){
    rt[tid] = etime[base+i0+tid];
    rg[tid] = sc4[(base+i0+tid)*4+1];
    rl[tid] = sc4[(base+i0+tid)*4+3];
  }
  __syncthreads();
  // phase 1: score tile (fast transcendentals; causal zeros exact in bf16)
  for (int e = tid; e < ITILE*L_; e += 256){
    int r = e >> 9, j = e & (L_-1);
    float v = 0.f;
    if (j < i0 + r){
      float gate = __frcp_rn(1.f + __expf(-(jg[j] + rg[r] + bg)));
      float ls   = softplus_fast(jl[j] + rl[r] + blv) + 1e-6f;
      float d    = rt[r] - jt[j];
      float t2   = 2.f*ls*ls;
      v = gate * t2 * __frcp_rn(t2 + d*d);
    }
    scb[r*SCSTR + j] = (uint16_t)f2bf(v);
  }
  __syncthreads();
  // phase 2: hidden[16][H] = scores @ hv  (MFMA 16x16x32, B from hvT short8)
  int wave = tid>>6, lane = tid&63, q = lane>>4, col = lane&15;
  for (int nt = wave; nt < NTIL; nt += 4){
    int n = nt*16 + col;
    const uint16_t* bT = hvT + ((size_t)b*HPAD + n)*L_;   // 144 rows, pad rows zero
    // issue all 16 B-loads (independent), then MFMA chain
    short8 bfr[16];
    #pragma unroll
    for (int kt = 0; kt < 16; ++kt)
      bfr[kt] = *(const short8*)&bT[kt*32 + q*8];          // B[k][n]
    float4v acc = {0.f,0.f,0.f,0.f};
    #pragma unroll
    for (int kt = 0; kt < 16; ++kt){
      short8 af = *(const short8*)&scb[col*SCSTR + kt*32 + q*8];  // A[m=col][k]
      acc = __builtin_amdgcn_mfma_f32_16x16x32_bf16(af, bfr[kt], acc, 0, 0, 0);
    }
    if (n < H_){
      #pragma unroll
      for (int rr = 0; rr < 4; ++rr)
        hid[(q*4+rr)*HIDS + n] = acc[rr];    // C/D: row=q*4+rr, col=n
    }
  }
  __syncthreads();
  // LayerNorm stats
  #pragma unroll
  for (int rr = 0; rr < 4; ++rr){
    int r = wave*4 + rr;
    float x0 = hid[r*HIDS + lane];
    float x1 = hid[r*HIDS + 64 + lane];
    float x2 = (lane<4) ? hid[r*HIDS + 128 + lane] : 0.f;
    float s1 = x0+x1+x2, s2 = x0*x0+x1*x1+x2*x2;
    #pragma unroll
    for (int m=32; m; m>>=1){ s1 += __shfl_xor(s1, m, 64); s2 += __shfl_xor(s2, m, 64); }
    if (lane == 0){
      float mu = s1 * (1.f/132.f);
      float var = s2 * (1.f/132.f) - mu*mu;
      mur[r] = mu; rsr[r] = rsqrtf(var + 1e-6f);
    }
  }
  __syncthreads();
  if (tid < HNLS){
    if (tid < H_){
      float g = gamma[tid], be = beta[tid];
      #pragma unroll 4
      for (int r = 0; r < ITILE; ++r)
        hnl[r*HNLS + tid] = (uint16_t)f2bf((hid[r*HIDS+tid]-mur[r])*rsr[r]*g + be);
    } else {
      #pragma unroll 4
      for (int r = 0; r < ITILE; ++r) hnl[r*HNLS + tid] = 0;
    }
  }
  __syncthreads();
  // fused decoder: hn(16x132) @ wd(152x132)^T -> cvec + logits
  short8 afr[KCH];
  #pragma unroll
  for (int kc = 0; kc < KCH; ++kc)
    afr[kc] = *(const short8*)&hnl[col*HNLS + kc*32 + q*8];   // A[m=col][k]
  for (int nt = wave; nt < NTIL3; nt += 4){
    float4v acc = {0.f,0.f,0.f,0.f};
    const short8* bp = (const short8*)&wd[(nt*16+col)*KSTR];
    #pragma unroll
    for (int kc = 0; kc < KCH; ++kc){
      // kc=4,q>0 reads past wd row end: A zero at k>=132 -- harmless
      short8 bfr = bp[kc*4 + q];
      acc = __builtin_amdgcn_mfma_f32_16x16x32_bf16(afr[kc], bfr, acc, 0, 0, 0);
    }
    int n = nt*16 + col;
    #pragma unroll
    for (int rr = 0; rr < 4; ++rr){
      int lr = q*4 + rr;
      if (n < H_)            cvec[(size_t)(base+i0+lr)*H_ + n] = acc[rr];
      else if (n < H_+NT_)   logit[lr*NT_ + (n-H_)] = acc[rr];
    }
  }
  __syncthreads();
  if (tid < ITILE){
    float mx = -1e30f;
    #pragma unroll
    for (int j=0;j<NT_;++j) mx = fmaxf(mx, logit[tid*NT_+j]);
    float ex[NT_]; float ssum = 0.f;
    #pragma unroll
    for (int j=0;j<NT_;++j){ ex[j] = __expf(logit[tid*NT_+j]-mx); ssum += ex[j]; }
    float inv = __frcp_rn(ssum);
    #pragma unroll
    for (int j=0;j<NT_;++j)
      outp[(size_t)(B_*L_) + (size_t)(base+i0+tid)*NT_ + j] = ex[j]*inv;
  }
}

// ---------------- K4: GAN sampler (fused; at VALU-issue floor) ----------------
__global__ __launch_bounds__(512, 6) void k4_sampler(
    const uint16_t* __restrict__ wbf, const float* __restrict__ cvec,
    const float* __restrict__ wt, const float* __restrict__ rs,
    float* __restrict__ outmean){
  __shared__ __align__(16) short Wlds[WBF_N];
  __shared__ __align__(16) float clds[16*CSTR];
  __shared__ float wtlds[HPAD];
  __shared__ float part[128];
  int tid = threadIdx.x, lane = tid & 63;
  int l0 = blockIdx.x*16, b = blockIdx.y, sch = blockIdx.z;
  int bl0 = b*L_ + l0;

  {   // stage W: flat 2448 x 16B vector copy
    const uint4v* g = (const uint4v*)wbf;
    uint4v* l = (uint4v*)Wlds;
    for (int idx = tid; idx < WBF_N/8; idx += 512) l[idx] = g[idx];
  }
  for (int m = tid>>6; m < 16; m += 8){
    for (int n = lane; n < CSTR; n += 64){
      float v = 0.f;
      if (n < H_) v = cvec[(size_t)(bl0+m)*H_ + n] - rs[n];
      clds[m*CSTR + n] = v;
    }
  }
  if (tid < HPAD) wtlds[tid] = (tid < H_) ? wt[tid] : 0.f;
  if (tid < 128) part[tid] = 0.f;
  __syncthreads();

  int wave = tid >> 6;
  int q = lane >> 4, col = lane & 15;
  int s = sch*8 + wave;
  if (s < SMP_){
    uint32_t fbase = (uint32_t)(bl0 + col)*(uint32_t)(SMP_*H_)
                   + (uint32_t)s*(uint32_t)H_ + (uint32_t)(q*8);
    uint4v afu[KCH];
    #pragma unroll
    for (int kc = 0; kc < 4; ++kc){
      #pragma unroll
      for (int t = 0; t < 4; ++t)
        afu[kc][t] = tfpair(fbase + (uint32_t)(kc*32 + 2*t),
                            fbase + (uint32_t)(kc*32 + 2*t + 1));
    }
    {
      uint4v a4 = {0u,0u,0u,0u};
      if (q == 0){
        a4[0] = tfpair(fbase + 128u, fbase + 129u);
        a4[1] = tfpair(fbase + 130u, fbase + 131u);
      }
      afu[4] = a4;
    }
    float racc0=0.f, racc1=0.f, racc2=0.f, racc3=0.f;
    for (int nt = 0; nt < NTIL; ++nt){
      float4v acc = {0.f,0.f,0.f,0.f};
      const short8* bp = (const short8*)&Wlds[(nt*16+col)*KSTR];
      #pragma unroll
      for (int kc = 0; kc < KCH; ++kc){
        short8 bfr = bp[kc*4 + q];
        acc = __builtin_amdgcn_mfma_f32_16x16x32_bf16(
                 __builtin_bit_cast(short8, afu[kc]), bfr, acc, 0, 0, 0);
      }
      int n = nt*16 + col;
      float wv = wtlds[n];
      const float* cb = &clds[(q*4)*CSTR + n];
      racc0 += fmaxf(acc[0] + cb[0*CSTR], 0.f)*wv;
      racc1 += fmaxf(acc[1] + cb[1*CSTR], 0.f)*wv;
      racc2 += fmaxf(acc[2] + cb[2*CSTR], 0.f)*wv;
      racc3 += fmaxf(acc[3] + cb[3*CSTR], 0.f)*wv;
    }
    #pragma unroll
    for (int m = 1; m < 16; m <<= 1){
      racc0 += __shfl_xor(racc0, m, 64);
      racc1 += __shfl_xor(racc1, m, 64);
      racc2 += __shfl_xor(racc2, m, 64);
      racc3 += __shfl_xor(racc3, m, 64);
    }
    if (col == 0){
      part[wave*16 + q*4 + 0] = 0.02f * softplus_f(racc0);
      part[wave*16 + q*4 + 1] = 0.02f * softplus_f(racc1);
      part[wave*16 + q*4 + 2] = 0.02f * softplus_f(racc2);
      part[wave*16 + q*4 + 3] = 0.02f * softplus_f(racc3);
    }
  }
  __syncthreads();
  if (tid < 16){
    float v = 0.f;
    #pragma unroll
    for (int w = 0; w < 8; ++w) v += part[w*16 + tid];
    atomicAdd(&outmean[bl0 + tid], v);
  }
}

// ---------------- launch ----------------
extern "C" void kernel_launch(void* const* d_in, const int* in_sizes, int n_in,
                              void* d_out, int out_size, void* d_ws, size_t ws_size,
                              hipStream_t stream){
  const int*   etype = (const int*)  d_in[0];
  const float* etime = (const float*)d_in[1];
  const float* Wt    = (const float*)d_in[3];
  const float* temb  = (const float*)d_in[4];
  const float* Wg    = (const float*)d_in[5];
  const float* bgp   = (const float*)d_in[6];
  const float* Wl    = (const float*)d_in[7];
  const float* blp   = (const float*)d_in[8];
  const float* gamma = (const float*)d_in[9];
  const float* beta  = (const float*)d_in[10];
  const float* Win   = (const float*)d_in[11];
  const float* Wn    = (const float*)d_in[12];
  const float* wtm   = (const float*)d_in[13];
  const float* Wpred = (const float*)d_in[14];
  float* out = (float*)d_out;

  uint16_t* hvT   = (uint16_t*)d_ws;                        // 32*144*512 shorts
  float*    sc4   = (float*)(hvT + (size_t)B_*HPAD*L_);     // 16384*4 floats
  float*    cvec  = sc4 + (size_t)16384*4;                  // 16384*132 floats
  float*    rs    = cvec + (size_t)16384*H_;                // 132 (+pad to 256)
  uint16_t* wbf   = (uint16_t*)(rs + 256);                  // HPAD*KSTR shorts
  uint16_t* wd    = wbf + (size_t)WBF_N;                    // WDROW*KSTR shorts

  k0_embed  <<<dim3(147),       dim3(256), 0, stream>>>(etype, etime, Wt, temb, Wg, Wl,
                                                        Wn, Win, Wpred, hvT, sc4, out, wbf, wd, rs);
  k1_attn   <<<dim3(32,32),     dim3(256), 0, stream>>>(etime, sc4, hvT, wd, bgp, blp,
                                                        gamma, beta, cvec, out);
  k4_sampler<<<dim3(32,32,7),   dim3(512), 0, stream>>>(wbf, cvec, wtm, rs, out);
}